// Round 1
// baseline (1589.728 us; speedup 1.0000x reference)
//
#include <hip/hip_runtime.h>
#include <hip/hip_bf16.h>

#define NNODES 100000
#define NEDGES 1600000
#define INF 512
#define OUTF 128

typedef __attribute__((ext_vector_type(8))) __bf16 bf16x8;
typedef __attribute__((ext_vector_type(4))) float f32x4;
typedef __attribute__((ext_vector_type(2))) float f32x2;

// ---------------- degree histogram (float counts, exact up to 2^24) --------
__global__ void deg_kernel(const int* __restrict__ src, const int* __restrict__ dst,
                           float* __restrict__ outdeg, float* __restrict__ indeg) {
  int stride = gridDim.x * blockDim.x;
  for (int i = blockIdx.x * blockDim.x + threadIdx.x; i < NEDGES; i += stride) {
    unsafeAtomicAdd(&outdeg[src[i]], 1.0f);
    unsafeAtomicAdd(&indeg[dst[i]], 1.0f);
  }
}

// ---------------- transpose+convert weight [512][128] f32 -> Wt bf16 [128][512]
__global__ void wt_kernel(const float* __restrict__ w, unsigned short* __restrict__ wt) {
  int i = blockIdx.x * blockDim.x + threadIdx.x;
  if (i < OUTF * INF) {
    int n = i >> 9;        // 0..127
    int k = i & 511;       // 0..511
    __bf16 b = (__bf16)(w[k * OUTF + n]);
    wt[i] = __builtin_bit_cast(unsigned short, b);
  }
}

// ---------------- h = (feat * rsqrt(outdeg)) @ W, bf16 MFMA -----------------
// block = 256 thr = 4 waves; block tile 128 rows x 128 cols; wave tile 32x128
__global__ __launch_bounds__(256) void gemm_kernel(
    const float* __restrict__ feat, const unsigned short* __restrict__ wt,
    const float* __restrict__ outdeg, float* __restrict__ h) {
  const int lane = threadIdx.x & 63;
  const int wave = threadIdx.x >> 6;
  const int l15 = lane & 15;
  const int lg  = lane >> 4;            // 0..3 (k-group)
  const int rowbase = blockIdx.x * 128 + wave * 32;

  int r0 = rowbase + l15;
  int r1 = rowbase + 16 + l15;
  float s0 = (r0 < NNODES) ? rsqrtf(fmaxf(outdeg[r0], 1.0f)) : 0.0f;
  float s1 = (r1 < NNODES) ? rsqrtf(fmaxf(outdeg[r1], 1.0f)) : 0.0f;
  const float* fp0 = feat + (size_t)(r0 < NNODES ? r0 : 0) * INF + lg * 8;
  const float* fp1 = feat + (size_t)(r1 < NNODES ? r1 : 0) * INF + lg * 8;

  f32x4 acc[2][8];
#pragma unroll
  for (int f = 0; f < 2; ++f)
#pragma unroll
    for (int c = 0; c < 8; ++c) acc[f][c] = (f32x4){0.f, 0.f, 0.f, 0.f};

#pragma unroll 2
  for (int k0 = 0; k0 < INF; k0 += 32) {
    f32x4 u0 = *(const f32x4*)(fp0 + k0);
    f32x4 v0 = *(const f32x4*)(fp0 + k0 + 4);
    f32x4 u1 = *(const f32x4*)(fp1 + k0);
    f32x4 v1 = *(const f32x4*)(fp1 + k0 + 4);
    bf16x8 a0, a1;
#pragma unroll
    for (int j = 0; j < 4; ++j) {
      a0[j]     = (__bf16)(u0[j] * s0);
      a0[j + 4] = (__bf16)(v0[j] * s0);
      a1[j]     = (__bf16)(u1[j] * s1);
      a1[j + 4] = (__bf16)(v1[j] * s1);
    }
    const unsigned short* bp = wt + l15 * INF + k0 + lg * 8;
#pragma unroll
    for (int c = 0; c < 8; ++c) {
      bf16x8 b = *(const bf16x8*)(bp + c * 16 * INF);
      acc[0][c] = __builtin_amdgcn_mfma_f32_16x16x32_bf16(a0, b, acc[0][c], 0, 0, 0);
      acc[1][c] = __builtin_amdgcn_mfma_f32_16x16x32_bf16(a1, b, acc[1][c], 0, 0, 0);
    }
  }

#pragma unroll
  for (int f = 0; f < 2; ++f) {
    int rb = rowbase + f * 16 + lg * 4;
#pragma unroll
    for (int r = 0; r < 4; ++r) {
      int row = rb + r;
      if (row < NNODES) {
#pragma unroll
        for (int c = 0; c < 8; ++c)
          h[(size_t)row * OUTF + c * 16 + l15] = acc[f][c][r];
      }
    }
  }
}

// ---------------- edge scatter: out[dst] += h[src] * ew ---------------------
// one wave per edge; lane j handles features 2j, 2j+1
__global__ void scatter_kernel(const int* __restrict__ src, const int* __restrict__ dst,
                               const float* __restrict__ ew, const float* __restrict__ h,
                               float* __restrict__ out) {
  int gw = (blockIdx.x * blockDim.x + threadIdx.x) >> 6;
  int lane = threadIdx.x & 63;
  int nw = (gridDim.x * blockDim.x) >> 6;
  for (int e = gw; e < NEDGES; e += nw) {
    int s = src[e];
    int d = dst[e];
    float w = ew[e];
    f32x2 v = *((const f32x2*)(h + (size_t)s * OUTF) + lane);
    float* op = out + (size_t)d * OUTF + lane * 2;
    unsafeAtomicAdd(op, v.x * w);
    unsafeAtomicAdd(op + 1, v.y * w);
  }
}

// ---------------- out = out * rsqrt(indeg) + bias ---------------------------
__global__ void final_kernel(const float* __restrict__ indeg, const float* __restrict__ bias,
                             float* __restrict__ out) {
  const int total = NNODES * OUTF / 4;
  int stride = gridDim.x * blockDim.x;
  for (int i = blockIdx.x * blockDim.x + threadIdx.x; i < total; i += stride) {
    int row = i >> 5;            // 32 float4 per row
    int cb = (i & 31) * 4;
    f32x4 v = ((const f32x4*)out)[i];
    f32x4 b = *(const f32x4*)(bias + cb);
    float sc = rsqrtf(fmaxf(indeg[row], 1.0f));
    ((f32x4*)out)[i] = v * sc + b;
  }
}

extern "C" void kernel_launch(void* const* d_in, const int* in_sizes, int n_in,
                              void* d_out, int out_size, void* d_ws, size_t ws_size,
                              hipStream_t stream) {
  const float* feat   = (const float*)d_in[0];
  const float* weight = (const float*)d_in[1];
  const float* bias   = (const float*)d_in[2];
  const float* ew     = (const float*)d_in[3];
  const int*   src    = (const int*)d_in[4];
  const int*   dst    = (const int*)d_in[5];
  float* out = (float*)d_out;
  char* ws = (char*)d_ws;

  float* outdeg      = (float*)ws;                      // 400 KB
  float* indeg       = (float*)(ws + (1u << 19));       // 400 KB
  unsigned short* wt = (unsigned short*)(ws + (1u << 20)); // 128 KB
  float* h           = (float*)(ws + (2u << 20));       // 51.2 MB

  hipMemsetAsync(outdeg, 0, NNODES * sizeof(float), stream);
  hipMemsetAsync(indeg, 0, NNODES * sizeof(float), stream);
  hipMemsetAsync(out, 0, (size_t)NNODES * OUTF * sizeof(float), stream);

  deg_kernel<<<2048, 256, 0, stream>>>(src, dst, outdeg, indeg);
  wt_kernel<<<(OUTF * INF + 255) / 256, 256, 0, stream>>>(weight, wt);
  gemm_kernel<<<(NNODES + 127) / 128, 256, 0, stream>>>(feat, wt, outdeg, h);
  scatter_kernel<<<4096, 256, 0, stream>>>(src, dst, ew, h, out);
  final_kernel<<<2048, 256, 0, stream>>>(indeg, bias, out);
}

// Round 2
// 471.125 us; speedup vs baseline: 3.3743x; 3.3743x over previous
//
#include <hip/hip_runtime.h>
#include <hip/hip_bf16.h>

#define NNODES 100000
#define NEDGES 1600000
#define INF 512
#define OUTF 128
#define SCAN_BS 512
#define NBLK ((NNODES + SCAN_BS - 1) / SCAN_BS)   // 196

typedef __attribute__((ext_vector_type(8))) __bf16 bf16x8;
typedef __attribute__((ext_vector_type(4))) float f32x4;
typedef __attribute__((ext_vector_type(2))) float f32x2;

// ---------------- degree histogram (int counts) -----------------------------
__global__ void count_kernel(const int* __restrict__ src, const int* __restrict__ dst,
                             int* __restrict__ out_cnt, int* __restrict__ in_cnt) {
  int stride = gridDim.x * blockDim.x;
  for (int i = blockIdx.x * blockDim.x + threadIdx.x; i < NEDGES; i += stride) {
    atomicAdd(&out_cnt[src[i]], 1);
    atomicAdd(&in_cnt[dst[i]], 1);
  }
}

// ---------------- transpose+convert weight [512][128] f32 -> Wt bf16 [128][512]
__global__ void wt_kernel(const float* __restrict__ w, unsigned short* __restrict__ wt) {
  int i = blockIdx.x * blockDim.x + threadIdx.x;
  if (i < OUTF * INF) {
    int n = i >> 9;
    int k = i & 511;
    __bf16 b = (__bf16)(w[k * OUTF + n]);
    wt[i] = __builtin_bit_cast(unsigned short, b);
  }
}

// ---------------- scan step 1: per-block sum of in_cnt ----------------------
__global__ __launch_bounds__(SCAN_BS) void reduce_kernel(const int* __restrict__ in_cnt,
                                                         int* __restrict__ bsum) {
  __shared__ int s[SCAN_BS];
  int t = threadIdx.x;
  int i = blockIdx.x * SCAN_BS + t;
  s[t] = (i < NNODES) ? in_cnt[i] : 0;
  __syncthreads();
  for (int off = SCAN_BS / 2; off > 0; off >>= 1) {
    if (t < off) s[t] += s[t + off];
    __syncthreads();
  }
  if (t == 0) bsum[blockIdx.x] = s[0];
}

// ---------------- scan step 2: exclusive scan of 196 block sums (in place) --
__global__ __launch_bounds__(256) void scan_small_kernel(int* __restrict__ bsum,
                                                         int* __restrict__ rowptr) {
  __shared__ int s[256];
  int t = threadIdx.x;
  int v = (t < NBLK) ? bsum[t] : 0;
  s[t] = v;
  __syncthreads();
  for (int off = 1; off < 256; off <<= 1) {
    int x = (t >= off) ? s[t - off] : 0;
    __syncthreads();
    s[t] += x;
    __syncthreads();
  }
  if (t < NBLK) bsum[t] = s[t] - v;     // exclusive
  if (t == 0) rowptr[NNODES] = NEDGES;
}

// ---------------- scan step 3: block-local exclusive scan + offset ----------
__global__ __launch_bounds__(SCAN_BS) void scan_final_kernel(
    const int* __restrict__ in_cnt, const int* __restrict__ bsum,
    int* __restrict__ rowptr, int* __restrict__ cursor) {
  __shared__ int s[SCAN_BS];
  int t = threadIdx.x;
  int i = blockIdx.x * SCAN_BS + t;
  int v = (i < NNODES) ? in_cnt[i] : 0;
  s[t] = v;
  __syncthreads();
  for (int off = 1; off < SCAN_BS; off <<= 1) {
    int x = (t >= off) ? s[t - off] : 0;
    __syncthreads();
    s[t] += x;
    __syncthreads();
  }
  if (i < NNODES) {
    int rp = bsum[blockIdx.x] + s[t] - v;
    rowptr[i] = rp;
    cursor[i] = rp;
  }
}

// ---------------- h = (feat * rsqrt(out_deg)) @ W, bf16 MFMA ----------------
__global__ __launch_bounds__(256) void gemm_kernel(
    const float* __restrict__ feat, const unsigned short* __restrict__ wt,
    const int* __restrict__ out_cnt, float* __restrict__ h) {
  const int lane = threadIdx.x & 63;
  const int wave = threadIdx.x >> 6;
  const int l15 = lane & 15;
  const int lg  = lane >> 4;
  const int rowbase = blockIdx.x * 128 + wave * 32;

  int r0 = rowbase + l15;
  int r1 = rowbase + 16 + l15;
  float s0 = (r0 < NNODES) ? rsqrtf(fmaxf((float)out_cnt[r0], 1.0f)) : 0.0f;
  float s1 = (r1 < NNODES) ? rsqrtf(fmaxf((float)out_cnt[r1], 1.0f)) : 0.0f;
  const float* fp0 = feat + (size_t)(r0 < NNODES ? r0 : 0) * INF + lg * 8;
  const float* fp1 = feat + (size_t)(r1 < NNODES ? r1 : 0) * INF + lg * 8;

  f32x4 acc[2][8];
#pragma unroll
  for (int f = 0; f < 2; ++f)
#pragma unroll
    for (int c = 0; c < 8; ++c) acc[f][c] = (f32x4){0.f, 0.f, 0.f, 0.f};

#pragma unroll 2
  for (int k0 = 0; k0 < INF; k0 += 32) {
    f32x4 u0 = *(const f32x4*)(fp0 + k0);
    f32x4 v0 = *(const f32x4*)(fp0 + k0 + 4);
    f32x4 u1 = *(const f32x4*)(fp1 + k0);
    f32x4 v1 = *(const f32x4*)(fp1 + k0 + 4);
    bf16x8 a0, a1;
#pragma unroll
    for (int j = 0; j < 4; ++j) {
      a0[j]     = (__bf16)(u0[j] * s0);
      a0[j + 4] = (__bf16)(v0[j] * s0);
      a1[j]     = (__bf16)(u1[j] * s1);
      a1[j + 4] = (__bf16)(v1[j] * s1);
    }
    const unsigned short* bp = wt + l15 * INF + k0 + lg * 8;
#pragma unroll
    for (int c = 0; c < 8; ++c) {
      bf16x8 b = *(const bf16x8*)(bp + c * 16 * INF);
      acc[0][c] = __builtin_amdgcn_mfma_f32_16x16x32_bf16(a0, b, acc[0][c], 0, 0, 0);
      acc[1][c] = __builtin_amdgcn_mfma_f32_16x16x32_bf16(a1, b, acc[1][c], 0, 0, 0);
    }
  }

#pragma unroll
  for (int f = 0; f < 2; ++f) {
    int rb = rowbase + f * 16 + lg * 4;
#pragma unroll
    for (int r = 0; r < 4; ++r) {
      int row = rb + r;
      if (row < NNODES) {
#pragma unroll
        for (int c = 0; c < 8; ++c)
          h[(size_t)row * OUTF + c * 16 + l15] = acc[f][c][r];
      }
    }
  }
}

// ---------------- fill CSR: epair[p] = (src, ew) sorted by dst --------------
__global__ void fill_kernel(const int* __restrict__ src, const int* __restrict__ dst,
                            const float* __restrict__ ew, int* __restrict__ cursor,
                            int2* __restrict__ epair) {
  int stride = gridDim.x * blockDim.x;
  for (int e = blockIdx.x * blockDim.x + threadIdx.x; e < NEDGES; e += stride) {
    int d = dst[e];
    int p = atomicAdd(&cursor[d], 1);
    epair[p] = make_int2(src[e], __float_as_int(ew[e]));
  }
}

// ---------------- gather: out[v] = rsqrt(indeg)*sum_e h[src_e]*w_e + bias ---
// one wave per dst node; lane j owns output features 2j, 2j+1
__global__ __launch_bounds__(256) void gather_kernel(
    const int* __restrict__ rowptr, const int2* __restrict__ epair,
    const float* __restrict__ h, const float* __restrict__ bias,
    float* __restrict__ out) {
  int node = (blockIdx.x * blockDim.x + threadIdx.x) >> 6;
  int lane = threadIdx.x & 63;
  if (node >= NNODES) return;
  int beg = rowptr[node];
  int end = rowptr[node + 1];

  float ax = 0.f, ay = 0.f;
  for (int base = beg; base < end; base += 64) {
    int j = base + lane;
    int2 pr = make_int2(0, 0);
    if (j < end) pr = epair[j];
    int cnt = min(end - base, 64);
    int t = 0;
    for (; t + 4 <= cnt; t += 4) {
      int s0 = __shfl(pr.x, t);
      int s1 = __shfl(pr.x, t + 1);
      int s2 = __shfl(pr.x, t + 2);
      int s3 = __shfl(pr.x, t + 3);
      float w0 = __int_as_float(__shfl(pr.y, t));
      float w1 = __int_as_float(__shfl(pr.y, t + 1));
      float w2 = __int_as_float(__shfl(pr.y, t + 2));
      float w3 = __int_as_float(__shfl(pr.y, t + 3));
      f32x2 v0 = *((const f32x2*)(h + (size_t)s0 * OUTF) + lane);
      f32x2 v1 = *((const f32x2*)(h + (size_t)s1 * OUTF) + lane);
      f32x2 v2 = *((const f32x2*)(h + (size_t)s2 * OUTF) + lane);
      f32x2 v3 = *((const f32x2*)(h + (size_t)s3 * OUTF) + lane);
      ax += v0.x * w0 + v1.x * w1 + v2.x * w2 + v3.x * w3;
      ay += v0.y * w0 + v1.y * w1 + v2.y * w2 + v3.y * w3;
    }
    for (; t < cnt; ++t) {
      int s = __shfl(pr.x, t);
      float w = __int_as_float(__shfl(pr.y, t));
      f32x2 v = *((const f32x2*)(h + (size_t)s * OUTF) + lane);
      ax += v.x * w;
      ay += v.y * w;
    }
  }

  float sc = rsqrtf(fmaxf((float)(end - beg), 1.0f));
  f32x2 b = *((const f32x2*)bias + lane);
  f32x2 r;
  r.x = ax * sc + b.x;
  r.y = ay * sc + b.y;
  *((f32x2*)(out + (size_t)node * OUTF) + lane) = r;
}

extern "C" void kernel_launch(void* const* d_in, const int* in_sizes, int n_in,
                              void* d_out, int out_size, void* d_ws, size_t ws_size,
                              hipStream_t stream) {
  const float* feat   = (const float*)d_in[0];
  const float* weight = (const float*)d_in[1];
  const float* bias   = (const float*)d_in[2];
  const float* ew     = (const float*)d_in[3];
  const int*   src    = (const int*)d_in[4];
  const int*   dst    = (const int*)d_in[5];
  float* out = (float*)d_out;
  char* ws = (char*)d_ws;

  int* in_cnt        = (int*)ws;                         // 400 KB
  int* out_cnt       = (int*)(ws + 0x80000);             // 400 KB
  int* rowptr        = (int*)(ws + 0x100000);            // 400 KB + 4
  int* cursor        = (int*)(ws + 0x180000);            // 400 KB
  int* bsum          = (int*)(ws + 0x200000);            // 1 KB
  unsigned short* wt = (unsigned short*)(ws + 0x210000); // 128 KB
  int2* epair        = (int2*)(ws + 0x240000);           // 12.8 MB
  float* h           = (float*)(ws + 0x1000000);         // 51.2 MB

  hipMemsetAsync(in_cnt, 0, NNODES * sizeof(int), stream);
  hipMemsetAsync(out_cnt, 0, NNODES * sizeof(int), stream);

  count_kernel<<<2048, 256, 0, stream>>>(src, dst, out_cnt, in_cnt);
  wt_kernel<<<(OUTF * INF + 255) / 256, 256, 0, stream>>>(weight, wt);
  reduce_kernel<<<NBLK, SCAN_BS, 0, stream>>>(in_cnt, bsum);
  scan_small_kernel<<<1, 256, 0, stream>>>(bsum, rowptr);
  scan_final_kernel<<<NBLK, SCAN_BS, 0, stream>>>(in_cnt, bsum, rowptr, cursor);
  gemm_kernel<<<(NNODES + 127) / 128, 256, 0, stream>>>(feat, wt, out_cnt, h);
  fill_kernel<<<2048, 256, 0, stream>>>(src, dst, ew, cursor, epair);
  gather_kernel<<<(NNODES * 64 + 255) / 256, 256, 0, stream>>>(rowptr, epair, h, bias, out);
}

// Round 3
// 284.784 us; speedup vs baseline: 5.5822x; 1.6543x over previous
//
#include <hip/hip_runtime.h>
#include <hip/hip_bf16.h>

#define NNODES 100000
#define NEDGES 1600000
#define INF 512
#define OUTF 128
#define NB 391          // buckets of 256 nodes: bucket = dst >> 8
#define BCAP 5120       // mean 4096, sigma ~64 -> 16 sigma headroom
#define SEG 4096        // edges per block in bucket_kernel

typedef __attribute__((ext_vector_type(8))) __bf16 bf16x8;
typedef __attribute__((ext_vector_type(4))) float f32x4;
typedef __attribute__((ext_vector_type(2))) float f32x2;

// ---------------- transpose+convert weight [512][128] f32 -> Wt bf16 [128][512]
__global__ void wt_kernel(const float* __restrict__ w, unsigned short* __restrict__ wt) {
  int i = blockIdx.x * blockDim.x + threadIdx.x;
  if (i < OUTF * INF) {
    int n = i >> 9;
    int k = i & 511;
    __bf16 b = (__bf16)(w[k * OUTF + n]);
    wt[i] = __builtin_bit_cast(unsigned short, b);
  }
}

// ---------------- pass A: bucket edges by dst>>8, histogram src out-degree ---
__global__ __launch_bounds__(256) void bucket_kernel(
    const int* __restrict__ src, const int* __restrict__ dst,
    const float* __restrict__ ew, int* __restrict__ out_cnt,
    int* __restrict__ bucket_cnt, int2* __restrict__ bucket) {
  __shared__ int hist[NB];
  __shared__ int base[NB];
  int t = threadIdx.x;
  for (int i = t; i < NB; i += 256) hist[i] = 0;
  __syncthreads();
  int e0 = blockIdx.x * SEG;
  int e1 = min(e0 + SEG, NEDGES);
  for (int e = e0 + t; e < e1; e += 256) {
    atomicAdd(&out_cnt[src[e]], 1);
    atomicAdd(&hist[dst[e] >> 8], 1);
  }
  __syncthreads();
  for (int i = t; i < NB; i += 256) {
    int c = hist[i];
    base[i] = c ? atomicAdd(&bucket_cnt[i], c) : 0;
    hist[i] = 0;                       // reuse as cursor
  }
  __syncthreads();
  for (int e = e0 + t; e < e1; e += 256) {
    int d = dst[e];
    int b = d >> 8;
    int r = atomicAdd(&hist[b], 1);
    int2 en;
    en.x = ((d & 255) << 17) | src[e];  // src < 2^17
    en.y = __float_as_int(ew[e]);
    bucket[(size_t)b * BCAP + base[b] + r] = en;
  }
}

// ---------------- exclusive scan of bucket counts (1 block) -----------------
__global__ __launch_bounds__(512) void bscan_kernel(const int* __restrict__ bucket_cnt,
                                                    int* __restrict__ bucket_base,
                                                    int* __restrict__ rowptr) {
  __shared__ int s[512];
  int t = threadIdx.x;
  int v = (t < NB) ? bucket_cnt[t] : 0;
  s[t] = v;
  __syncthreads();
  for (int off = 1; off < 512; off <<= 1) {
    int x = (t >= off) ? s[t - off] : 0;
    __syncthreads();
    s[t] += x;
    __syncthreads();
  }
  if (t < NB) bucket_base[t] = s[t] - v;
  if (t == 0) rowptr[NNODES] = NEDGES;
}

// ---------------- pass B: bucket -> CSR (rowptr + epair) --------------------
__global__ __launch_bounds__(256) void csr_kernel(
    const int* __restrict__ bucket_cnt, const int* __restrict__ bucket_base,
    const int2* __restrict__ bucket, int* __restrict__ rowptr,
    int2* __restrict__ epair) {
  __shared__ int hist[256];
  __shared__ int cur[256];
  int b = blockIdx.x;
  int t = threadIdx.x;
  int nb = bucket_cnt[b];
  int bbase = bucket_base[b];
  const int2* bk = bucket + (size_t)b * BCAP;
  hist[t] = 0;
  __syncthreads();
  for (int i = t; i < nb; i += 256) atomicAdd(&hist[bk[i].x >> 17], 1);
  __syncthreads();
  int v = hist[t];
  for (int off = 1; off < 256; off <<= 1) {
    int x = (t >= off) ? hist[t - off] : 0;
    __syncthreads();
    hist[t] += x;
    __syncthreads();
  }
  int excl = hist[t] - v;
  int node = b * 256 + t;
  if (node < NNODES) rowptr[node] = bbase + excl;
  cur[t] = excl;
  __syncthreads();
  for (int i = t; i < nb; i += 256) {
    int2 en = bk[i];
    int nl = en.x >> 17;
    int r = atomicAdd(&cur[nl], 1);
    epair[bbase + r] = make_int2(en.x & 0x1FFFF, en.y);
  }
}

// ---------------- h = (feat * rsqrt(out_deg)) @ W, bf16 MFMA, bf16 out ------
__global__ __launch_bounds__(256) void gemm_kernel(
    const float* __restrict__ feat, const unsigned short* __restrict__ wt,
    const int* __restrict__ out_cnt, unsigned short* __restrict__ h) {
  const int lane = threadIdx.x & 63;
  const int wave = threadIdx.x >> 6;
  const int l15 = lane & 15;
  const int lg  = lane >> 4;
  const int rowbase = blockIdx.x * 128 + wave * 32;

  int r0 = rowbase + l15;
  int r1 = rowbase + 16 + l15;
  float s0 = (r0 < NNODES) ? rsqrtf(fmaxf((float)out_cnt[r0], 1.0f)) : 0.0f;
  float s1 = (r1 < NNODES) ? rsqrtf(fmaxf((float)out_cnt[r1], 1.0f)) : 0.0f;
  const float* fp0 = feat + (size_t)(r0 < NNODES ? r0 : 0) * INF + lg * 8;
  const float* fp1 = feat + (size_t)(r1 < NNODES ? r1 : 0) * INF + lg * 8;

  f32x4 acc[2][8];
#pragma unroll
  for (int f = 0; f < 2; ++f)
#pragma unroll
    for (int c = 0; c < 8; ++c) acc[f][c] = (f32x4){0.f, 0.f, 0.f, 0.f};

#pragma unroll 2
  for (int k0 = 0; k0 < INF; k0 += 32) {
    f32x4 u0 = *(const f32x4*)(fp0 + k0);
    f32x4 v0 = *(const f32x4*)(fp0 + k0 + 4);
    f32x4 u1 = *(const f32x4*)(fp1 + k0);
    f32x4 v1 = *(const f32x4*)(fp1 + k0 + 4);
    bf16x8 a0, a1;
#pragma unroll
    for (int j = 0; j < 4; ++j) {
      a0[j]     = (__bf16)(u0[j] * s0);
      a0[j + 4] = (__bf16)(v0[j] * s0);
      a1[j]     = (__bf16)(u1[j] * s1);
      a1[j + 4] = (__bf16)(v1[j] * s1);
    }
    const unsigned short* bp = wt + l15 * INF + k0 + lg * 8;
#pragma unroll
    for (int c = 0; c < 8; ++c) {
      bf16x8 b = *(const bf16x8*)(bp + c * 16 * INF);
      acc[0][c] = __builtin_amdgcn_mfma_f32_16x16x32_bf16(a0, b, acc[0][c], 0, 0, 0);
      acc[1][c] = __builtin_amdgcn_mfma_f32_16x16x32_bf16(a1, b, acc[1][c], 0, 0, 0);
    }
  }

#pragma unroll
  for (int f = 0; f < 2; ++f) {
    int rb = rowbase + f * 16 + lg * 4;
#pragma unroll
    for (int r = 0; r < 4; ++r) {
      int row = rb + r;
      if (row < NNODES) {
#pragma unroll
        for (int c = 0; c < 8; ++c) {
          __bf16 bv = (__bf16)acc[f][c][r];
          h[(size_t)row * OUTF + c * 16 + l15] = __builtin_bit_cast(unsigned short, bv);
        }
      }
    }
  }
}

// ---------------- gather: out[v] = rsqrt(indeg)*sum_e h[src_e]*w_e + bias ---
// one wave per dst node; lane j owns output features 2j, 2j+1 (one u32 = 2 bf16)
__global__ __launch_bounds__(256) void gather_kernel(
    const int* __restrict__ rowptr, const int2* __restrict__ epair,
    const unsigned short* __restrict__ h, const float* __restrict__ bias,
    float* __restrict__ out) {
  int node = (blockIdx.x * blockDim.x + threadIdx.x) >> 6;
  int lane = threadIdx.x & 63;
  if (node >= NNODES) return;
  int beg = rowptr[node];
  int end = rowptr[node + 1];

  float ax = 0.f, ay = 0.f;
  for (int base = beg; base < end; base += 64) {
    int j = base + lane;
    int2 pr = make_int2(0, 0);
    if (j < end) pr = epair[j];
    int cnt = min(end - base, 64);
    int t = 0;
    for (; t + 4 <= cnt; t += 4) {
      int s0 = __shfl(pr.x, t);
      int s1 = __shfl(pr.x, t + 1);
      int s2 = __shfl(pr.x, t + 2);
      int s3 = __shfl(pr.x, t + 3);
      float w0 = __int_as_float(__shfl(pr.y, t));
      float w1 = __int_as_float(__shfl(pr.y, t + 1));
      float w2 = __int_as_float(__shfl(pr.y, t + 2));
      float w3 = __int_as_float(__shfl(pr.y, t + 3));
      unsigned int u0 = *((const unsigned int*)(h + (size_t)s0 * OUTF) + lane);
      unsigned int u1 = *((const unsigned int*)(h + (size_t)s1 * OUTF) + lane);
      unsigned int u2 = *((const unsigned int*)(h + (size_t)s2 * OUTF) + lane);
      unsigned int u3 = *((const unsigned int*)(h + (size_t)s3 * OUTF) + lane);
      ax += __uint_as_float(u0 << 16) * w0 + __uint_as_float(u1 << 16) * w1 +
            __uint_as_float(u2 << 16) * w2 + __uint_as_float(u3 << 16) * w3;
      ay += __uint_as_float(u0 & 0xFFFF0000u) * w0 + __uint_as_float(u1 & 0xFFFF0000u) * w1 +
            __uint_as_float(u2 & 0xFFFF0000u) * w2 + __uint_as_float(u3 & 0xFFFF0000u) * w3;
    }
    for (; t < cnt; ++t) {
      int s = __shfl(pr.x, t);
      float w = __int_as_float(__shfl(pr.y, t));
      unsigned int u = *((const unsigned int*)(h + (size_t)s * OUTF) + lane);
      ax += __uint_as_float(u << 16) * w;
      ay += __uint_as_float(u & 0xFFFF0000u) * w;
    }
  }

  float sc = rsqrtf(fmaxf((float)(end - beg), 1.0f));
  f32x2 b = *((const f32x2*)bias + lane);
  f32x2 r;
  r.x = ax * sc + b.x;
  r.y = ay * sc + b.y;
  *((f32x2*)(out + (size_t)node * OUTF) + lane) = r;
}

extern "C" void kernel_launch(void* const* d_in, const int* in_sizes, int n_in,
                              void* d_out, int out_size, void* d_ws, size_t ws_size,
                              hipStream_t stream) {
  const float* feat   = (const float*)d_in[0];
  const float* weight = (const float*)d_in[1];
  const float* bias   = (const float*)d_in[2];
  const float* ew     = (const float*)d_in[3];
  const int*   src    = (const int*)d_in[4];
  const int*   dst    = (const int*)d_in[5];
  float* out = (float*)d_out;
  char* ws = (char*)d_ws;

  int* out_cnt        = (int*)ws;                          // 400 KB
  int* rowptr         = (int*)(ws + 0x80000);              // 400 KB + 4
  int* bucket_cnt     = (int*)(ws + 0x100000);             // 1.6 KB
  int* bucket_base    = (int*)(ws + 0x101000);             // 1.6 KB
  unsigned short* wt  = (unsigned short*)(ws + 0x110000);  // 128 KB
  int2* bucket        = (int2*)(ws + 0x140000);            // 16.0 MB
  int2* epair         = (int2*)(ws + 0x1200000);           // 12.8 MB
  unsigned short* h   = (unsigned short*)(ws + 0x2000000); // 25.6 MB

  hipMemsetAsync(out_cnt, 0, NNODES * sizeof(int), stream);
  hipMemsetAsync(bucket_cnt, 0, NB * sizeof(int), stream);

  wt_kernel<<<(OUTF * INF + 255) / 256, 256, 0, stream>>>(weight, wt);
  bucket_kernel<<<(NEDGES + SEG - 1) / SEG, 256, 0, stream>>>(src, dst, ew, out_cnt,
                                                              bucket_cnt, bucket);
  bscan_kernel<<<1, 512, 0, stream>>>(bucket_cnt, bucket_base, rowptr);
  csr_kernel<<<NB, 256, 0, stream>>>(bucket_cnt, bucket_base, bucket, rowptr, epair);
  gemm_kernel<<<(NNODES + 127) / 128, 256, 0, stream>>>(feat, wt, out_cnt, h);
  gather_kernel<<<(NNODES * 64 + 255) / 256, 256, 0, stream>>>(rowptr, epair, h, bias, out);
}

// Round 4
// 256.942 us; speedup vs baseline: 6.1871x; 1.1084x over previous
//
#include <hip/hip_runtime.h>
#include <hip/hip_bf16.h>

#define NNODES 100000
#define NEDGES 1600000
#define INF 512
#define OUTF 128
#define NB 391          // buckets of 256 nodes: bucket = dst >> 8
#define BCAP 5120       // mean 4096, sigma ~64 -> 16 sigma headroom
#define SEG 4096        // edges per block in bucket_kernel
#define BK 32           // gemm k-step (floats)
#define NKSTEP (INF / BK)

typedef __attribute__((ext_vector_type(8))) __bf16 bf16x8;
typedef __attribute__((ext_vector_type(4))) float f32x4;
typedef __attribute__((ext_vector_type(2))) float f32x2;

typedef const __attribute__((address_space(1))) unsigned int* gas_ptr;
typedef __attribute__((address_space(3))) unsigned int* las_ptr;

__device__ __forceinline__ void gload_lds16(const void* g, void* l) {
  __builtin_amdgcn_global_load_lds((gas_ptr)g, (las_ptr)l, 16, 0, 0);
}

// ---------------- weight f32 [512][128] -> bf16 fragment-ordered ------------
// layout: short index (((kb*8 + c)*16 + l15)*4 + lg)*8 + j
//         value = W[kb*32 + lg*8 + j][c*16 + l15]
__global__ void wt_kernel(const float* __restrict__ w, unsigned short* __restrict__ wta) {
  int i = blockIdx.x * blockDim.x + threadIdx.x;   // 0..8191
  if (i >= 8192) return;
  int lg  = i & 3;
  int l15 = (i >> 2) & 15;
  int c   = (i >> 6) & 7;
  int kb  = i >> 9;
  int n = c * 16 + l15;
  int kbase = kb * 32 + lg * 8;
  unsigned short tmp[8];
#pragma unroll
  for (int j = 0; j < 8; ++j) {
    __bf16 b = (__bf16)(w[(size_t)(kbase + j) * OUTF + n]);
    tmp[j] = __builtin_bit_cast(unsigned short, b);
  }
  ((int4*)wta)[i] = *(int4*)tmp;
}

// ---------------- pass A: bucket edges by dst>>8, histogram src out-degree ---
__global__ __launch_bounds__(256) void bucket_kernel(
    const int* __restrict__ src, const int* __restrict__ dst,
    const float* __restrict__ ew, int* __restrict__ out_cnt,
    int* __restrict__ bucket_cnt, int2* __restrict__ bucket) {
  __shared__ int hist[NB];
  __shared__ int base[NB];
  int t = threadIdx.x;
  for (int i = t; i < NB; i += 256) hist[i] = 0;
  __syncthreads();
  int e0 = blockIdx.x * SEG;
  int e1 = min(e0 + SEG, NEDGES);
  for (int e = e0 + t; e < e1; e += 256) {
    atomicAdd(&out_cnt[src[e]], 1);
    atomicAdd(&hist[dst[e] >> 8], 1);
  }
  __syncthreads();
  for (int i = t; i < NB; i += 256) {
    int c = hist[i];
    base[i] = c ? atomicAdd(&bucket_cnt[i], c) : 0;
    hist[i] = 0;                       // reuse as cursor
  }
  __syncthreads();
  for (int e = e0 + t; e < e1; e += 256) {
    int d = dst[e];
    int b = d >> 8;
    int r = atomicAdd(&hist[b], 1);
    int2 en;
    en.x = ((d & 255) << 17) | src[e];  // src < 2^17
    en.y = __float_as_int(ew[e]);
    bucket[(size_t)b * BCAP + base[b] + r] = en;
  }
}

// ---------------- exclusive scan of bucket counts (1 block) -----------------
__global__ __launch_bounds__(512) void bscan_kernel(const int* __restrict__ bucket_cnt,
                                                    int* __restrict__ bucket_base,
                                                    int* __restrict__ rowptr) {
  __shared__ int s[512];
  int t = threadIdx.x;
  int v = (t < NB) ? bucket_cnt[t] : 0;
  s[t] = v;
  __syncthreads();
  for (int off = 1; off < 512; off <<= 1) {
    int x = (t >= off) ? s[t - off] : 0;
    __syncthreads();
    s[t] += x;
    __syncthreads();
  }
  if (t < NB) bucket_base[t] = s[t] - v;
  if (t == 0) rowptr[NNODES] = NEDGES;
}

// ---------------- pass B: bucket -> CSR (rowptr + epair) --------------------
__global__ __launch_bounds__(256) void csr_kernel(
    const int* __restrict__ bucket_cnt, const int* __restrict__ bucket_base,
    const int2* __restrict__ bucket, int* __restrict__ rowptr,
    int2* __restrict__ epair) {
  __shared__ int hist[256];
  __shared__ int cur[256];
  int b = blockIdx.x;
  int t = threadIdx.x;
  int nb = bucket_cnt[b];
  int bbase = bucket_base[b];
  const int2* bk = bucket + (size_t)b * BCAP;
  hist[t] = 0;
  __syncthreads();
  for (int i = t; i < nb; i += 256) atomicAdd(&hist[bk[i].x >> 17], 1);
  __syncthreads();
  int v = hist[t];
  for (int off = 1; off < 256; off <<= 1) {
    int x = (t >= off) ? hist[t - off] : 0;
    __syncthreads();
    hist[t] += x;
    __syncthreads();
  }
  int excl = hist[t] - v;
  int node = b * 256 + t;
  if (node < NNODES) rowptr[node] = bbase + excl;
  cur[t] = excl;
  __syncthreads();
  for (int i = t; i < nb; i += 256) {
    int2 en = bk[i];
    int nl = en.x >> 17;
    int r = atomicAdd(&cur[nl], 1);
    epair[bbase + r] = make_int2(en.x & 0x1FFFF, en.y);
  }
}

// ---------------- h = (feat * rsqrt(out_deg)) @ W, LDS-staged MFMA ----------
// block tile 128 rows x 128 cols, BK=32; 4 waves, each 32 rows.
// A: LDS [128][32] f32, chunk(16B)-XOR-swizzled; staged via global_load_lds
//    with pre-swizzled per-lane global source (linear LDS dest).
// B: LDS 8KB bf16, fragment-ordered (wta layout), linear stage, lane-linear read.
__global__ __launch_bounds__(256, 3) void gemm_kernel(
    const float* __restrict__ feat, const unsigned short* __restrict__ wta,
    const int* __restrict__ out_cnt, unsigned short* __restrict__ h) {
  __shared__ float As[2][128 * BK];            // 16 KB each
  __shared__ unsigned short Bs[2][4096];       // 8 KB each

  const int t = threadIdx.x;
  const int lane = t & 63;
  const int wave = t >> 6;
  const int l15 = lane & 15;
  const int lg  = lane >> 4;
  const int rowbase = blockIdx.x * 128;

  // staging geometry (A): instr i = wave*4+q covers rows 8i..8i+7 of the tile
  const int srow_off = lane >> 3;              // 0..7
  const int schunk = (lane & 7) ^ srow_off;    // pre-swizzled source chunk

  // row scales for this wave's two row-fragments
  int r0 = rowbase + wave * 32 + l15;
  int r1 = r0 + 16;
  float s0 = rsqrtf(fmaxf((float)out_cnt[min(r0, NNODES - 1)], 1.0f));
  float s1 = rsqrtf(fmaxf((float)out_cnt[min(r1, NNODES - 1)], 1.0f));

  f32x4 acc[2][8];
#pragma unroll
  for (int f = 0; f < 2; ++f)
#pragma unroll
    for (int c = 0; c < 8; ++c) acc[f][c] = (f32x4){0.f, 0.f, 0.f, 0.f};

#define STAGE(buf, kb)                                                         \
  {                                                                            \
    _Pragma("unroll")                                                          \
    for (int q = 0; q < 4; ++q) {                                              \
      int gr = min(rowbase + wave * 32 + q * 8 + srow_off, NNODES - 1);        \
      const float* gsrc = feat + (size_t)gr * INF + (kb) * BK + schunk * 4;    \
      gload_lds16(gsrc, &As[buf][(wave * 4 + q) * 256]);                       \
    }                                                                          \
    _Pragma("unroll")                                                          \
    for (int q = 0; q < 2; ++q) {                                              \
      const unsigned short* gsrc =                                             \
          wta + (size_t)(kb) * 4096 + (wave * 2 + q) * 512 + lane * 8;         \
      gload_lds16(gsrc, &Bs[buf][(wave * 2 + q) * 512]);                       \
    }                                                                          \
  }

  int buf = 0;
  STAGE(0, 0);
  __syncthreads();

  for (int kb = 0; kb < NKSTEP; ++kb) {
    if (kb + 1 < NKSTEP) STAGE(buf ^ 1, kb + 1);

    // B fragments: lane-linear, conflict-free
    bf16x8 bfr[8];
#pragma unroll
    for (int c = 0; c < 8; ++c)
      bfr[c] = *(const bf16x8*)&Bs[buf][c * 512 + l15 * 32 + lg * 8];

    // A fragments: row = wave*32 + rf*16 + l15, logical chunks lg*2, lg*2+1
    bf16x8 afr[2];
#pragma unroll
    for (int rf = 0; rf < 2; ++rf) {
      int r = wave * 32 + rf * 16 + l15;
      int c0 = (lg * 2) ^ (l15 & 7);
      int c1 = (lg * 2 + 1) ^ (l15 & 7);
      f32x4 u = *(const f32x4*)&As[buf][r * 32 + c0 * 4];
      f32x4 v = *(const f32x4*)&As[buf][r * 32 + c1 * 4];
      float s = rf ? s1 : s0;
      bf16x8 a;
#pragma unroll
      for (int j = 0; j < 4; ++j) {
        a[j]     = (__bf16)(u[j] * s);
        a[j + 4] = (__bf16)(v[j] * s);
      }
      afr[rf] = a;
    }

#pragma unroll
    for (int c = 0; c < 8; ++c) {
      acc[0][c] = __builtin_amdgcn_mfma_f32_16x16x32_bf16(afr[0], bfr[c], acc[0][c], 0, 0, 0);
      acc[1][c] = __builtin_amdgcn_mfma_f32_16x16x32_bf16(afr[1], bfr[c], acc[1][c], 0, 0, 0);
    }

    __syncthreads();
    buf ^= 1;
  }
#undef STAGE

#pragma unroll
  for (int f = 0; f < 2; ++f) {
    int rb = rowbase + wave * 32 + f * 16 + lg * 4;
#pragma unroll
    for (int r = 0; r < 4; ++r) {
      int row = rb + r;
      if (row < NNODES) {
#pragma unroll
        for (int c = 0; c < 8; ++c) {
          __bf16 bv = (__bf16)acc[f][c][r];
          h[(size_t)row * OUTF + c * 16 + l15] = __builtin_bit_cast(unsigned short, bv);
        }
      }
    }
  }
}

// ---------------- gather: out[v] = rsqrt(indeg)*sum_e h[src_e]*w_e + bias ---
// one wave per dst node; lane j owns output features 2j, 2j+1 (one u32 = 2 bf16)
__global__ __launch_bounds__(256) void gather_kernel(
    const int* __restrict__ rowptr, const int2* __restrict__ epair,
    const unsigned short* __restrict__ h, const float* __restrict__ bias,
    float* __restrict__ out) {
  int node = (blockIdx.x * blockDim.x + threadIdx.x) >> 6;
  int lane = threadIdx.x & 63;
  if (node >= NNODES) return;
  int beg = rowptr[node];
  int end = rowptr[node + 1];

  float ax = 0.f, ay = 0.f;
  for (int base = beg; base < end; base += 64) {
    int j = base + lane;
    int2 pr = make_int2(0, 0);
    if (j < end) pr = epair[j];
    int cnt = min(end - base, 64);
    int t = 0;
    for (; t + 4 <= cnt; t += 4) {
      int s0 = __shfl(pr.x, t);
      int s1 = __shfl(pr.x, t + 1);
      int s2 = __shfl(pr.x, t + 2);
      int s3 = __shfl(pr.x, t + 3);
      float w0 = __int_as_float(__shfl(pr.y, t));
      float w1 = __int_as_float(__shfl(pr.y, t + 1));
      float w2 = __int_as_float(__shfl(pr.y, t + 2));
      float w3 = __int_as_float(__shfl(pr.y, t + 3));
      unsigned int u0 = *((const unsigned int*)(h + (size_t)s0 * OUTF) + lane);
      unsigned int u1 = *((const unsigned int*)(h + (size_t)s1 * OUTF) + lane);
      unsigned int u2 = *((const unsigned int*)(h + (size_t)s2 * OUTF) + lane);
      unsigned int u3 = *((const unsigned int*)(h + (size_t)s3 * OUTF) + lane);
      ax += __uint_as_float(u0 << 16) * w0 + __uint_as_float(u1 << 16) * w1 +
            __uint_as_float(u2 << 16) * w2 + __uint_as_float(u3 << 16) * w3;
      ay += __uint_as_float(u0 & 0xFFFF0000u) * w0 + __uint_as_float(u1 & 0xFFFF0000u) * w1 +
            __uint_as_float(u2 & 0xFFFF0000u) * w2 + __uint_as_float(u3 & 0xFFFF0000u) * w3;
    }
    for (; t < cnt; ++t) {
      int s = __shfl(pr.x, t);
      float w = __int_as_float(__shfl(pr.y, t));
      unsigned int u = *((const unsigned int*)(h + (size_t)s * OUTF) + lane);
      ax += __uint_as_float(u << 16) * w;
      ay += __uint_as_float(u & 0xFFFF0000u) * w;
    }
  }

  float sc = rsqrtf(fmaxf((float)(end - beg), 1.0f));
  f32x2 b = *((const f32x2*)bias + lane);
  f32x2 r;
  r.x = ax * sc + b.x;
  r.y = ay * sc + b.y;
  *((f32x2*)(out + (size_t)node * OUTF) + lane) = r;
}

extern "C" void kernel_launch(void* const* d_in, const int* in_sizes, int n_in,
                              void* d_out, int out_size, void* d_ws, size_t ws_size,
                              hipStream_t stream) {
  const float* feat   = (const float*)d_in[0];
  const float* weight = (const float*)d_in[1];
  const float* bias   = (const float*)d_in[2];
  const float* ew     = (const float*)d_in[3];
  const int*   src    = (const int*)d_in[4];
  const int*   dst    = (const int*)d_in[5];
  float* out = (float*)d_out;
  char* ws = (char*)d_ws;

  int* out_cnt        = (int*)ws;                          // 400 KB
  int* rowptr         = (int*)(ws + 0x80000);              // 400 KB + 4
  int* bucket_cnt     = (int*)(ws + 0x100000);             // 1.6 KB
  int* bucket_base    = (int*)(ws + 0x101000);             // 1.6 KB
  unsigned short* wta = (unsigned short*)(ws + 0x110000);  // 128 KB
  int2* bucket        = (int2*)(ws + 0x140000);            // 16.0 MB
  int2* epair         = (int2*)(ws + 0x1200000);           // 12.8 MB
  unsigned short* h   = (unsigned short*)(ws + 0x2000000); // 25.6 MB

  hipMemsetAsync(out_cnt, 0, NNODES * sizeof(int), stream);
  hipMemsetAsync(bucket_cnt, 0, NB * sizeof(int), stream);

  wt_kernel<<<32, 256, 0, stream>>>(weight, wta);
  bucket_kernel<<<(NEDGES + SEG - 1) / SEG, 256, 0, stream>>>(src, dst, ew, out_cnt,
                                                              bucket_cnt, bucket);
  bscan_kernel<<<1, 512, 0, stream>>>(bucket_cnt, bucket_base, rowptr);
  csr_kernel<<<NB, 256, 0, stream>>>(bucket_cnt, bucket_base, bucket, rowptr, epair);
  gemm_kernel<<<(NNODES + 127) / 128, 256, 0, stream>>>(feat, wta, out_cnt, h);
  gather_kernel<<<(NNODES * 64 + 255) / 256, 256, 0, stream>>>(rowptr, epair, h, bias, out);
}